// Round 2
// baseline (2129.074 us; speedup 1.0000x reference)
//
#include <hip/hip_runtime.h>

// trajectory2seq round 2.
// enc_kernel: 128 blocks x 640 thr (10 waves). Wave w owns hidden units {w, w+10}
//   for BOTH GRU layers; layer1 pipelined one timestep behind layer0 -> ONE
//   barrier per iteration (129 total). Weights are wave-uniform -> s_load.
//   h-state transposed [k][b] in LDS (stride-1 lanes, conflict-free), dbuffered.
// dec_kernel: 256 blocks x 32 batch x 512 thr (16 half-wave slots) -> all CUs.
// ws layout: enc [128][20][8192] fp32 + hfin0/hfin1 [8192][20].

#define HN 20
#define DIN 64
#define NVOCAB 128
#define NB 8192
#define NS 128
#define NDEC 6

#define HID_OFF (NB * NDEC * NVOCAB)      // 6291456
#define ATTN_OFF (HID_OFF + 2 * NB * HN)  // 6619136

__device__ __forceinline__ float sigf(float x) {
    return 1.0f / (1.0f + __expf(-x));
}
__device__ __forceinline__ float tanh_fast(float x) {
    // 1 - 2/(1+e^{2x}); saturates correctly at +/-inf, no branches
    return 1.0f - 2.0f / (1.0f + __expf(2.0f * x));
}

__global__ __launch_bounds__(640)
void enc_kernel(const float* __restrict__ x,
                const float* __restrict__ Wih0, const float* __restrict__ Whh0,
                const float* __restrict__ bih0, const float* __restrict__ bhh0,
                const float* __restrict__ Wih1, const float* __restrict__ Whh1,
                const float* __restrict__ bih1, const float* __restrict__ bhh1,
                float* __restrict__ enc, float* __restrict__ hf0,
                float* __restrict__ hf1)
{
    __shared__ float xs[2][64][68];      // x tile, dbuf; per-lane-row f4 reads (stride 68: measured conflict-free)
    __shared__ float h0s[2][HN][64];     // transposed: [k][batch], lane-stride-1
    __shared__ float h1s[2][HN][64];

    const int tid = threadIdx.x;
    const int l   = tid & 63;
    const int w   = __builtin_amdgcn_readfirstlane(tid >> 6);  // 0..9
    const int b0  = blockIdx.x * 64;
    const int b   = b0 + l;
    const int k0  = w;
    const int k1  = w + 10;

    for (int i = tid; i < 2 * HN * 64; i += 640) {
        (&h0s[0][0][0])[i] = 0.0f;
        (&h1s[0][0][0])[i] = 0.0f;
    }
    {   // stage x(t=0)
        const float4* xv = (const float4*)x;
        for (int c = tid; c < 1024; c += 640) {
            int r = c >> 4, qq = c & 15;
            *(float4*)(&xs[0][r][qq * 4]) = xv[((size_t)(b0 + r) * NS + 0) * 16 + qq];
        }
    }
    __syncthreads();

    int p = 0;
    for (int u = 0; u <= NS; ++u) {
        const int q = p ^ 1;

        // ---- prefetch x(u+1) into xs[q] ----
        if (u + 1 < NS) {
            const float4* xv = (const float4*)x;
            for (int c = tid; c < 1024; c += 640) {
                int r = c >> 4, qq = c & 15;
                *(float4*)(&xs[q][r][qq * 4]) = xv[((size_t)(b0 + r) * NS + (u + 1)) * 16 + qq];
            }
        }

        // h0(u-1): needed by L0 (u<NS) and L1 (u>=1)
        float h0r[HN];
        #pragma unroll
        for (int i = 0; i < HN; ++i) h0r[i] = h0s[p][i][l];

        if (u < NS) {
            // ---- layer 0: h0(u) for k0,k1 ----
            float xr[DIN];
            #pragma unroll
            for (int qq = 0; qq < 16; ++qq) {
                float4 v = *(const float4*)(&xs[p][l][qq * 4]);
                xr[4*qq] = v.x; xr[4*qq+1] = v.y; xr[4*qq+2] = v.z; xr[4*qq+3] = v.w;
            }
            #pragma unroll
            for (int c = 0; c < 2; ++c) {
                const int kk = (c == 0) ? k0 : k1;
                float ar = bih0[kk], az = bih0[20 + kk], an = bih0[40 + kk];
                #pragma unroll
                for (int i = 0; i < DIN; ++i) {
                    ar += Wih0[kk * DIN + i] * xr[i];
                    az += Wih0[(20 + kk) * DIN + i] * xr[i];
                    an += Wih0[(40 + kk) * DIN + i] * xr[i];
                }
                float hr = bhh0[kk], hz = bhh0[20 + kk], hn = bhh0[40 + kk];
                #pragma unroll
                for (int i = 0; i < HN; ++i) {
                    hr += Whh0[kk * HN + i] * h0r[i];
                    hz += Whh0[(20 + kk) * HN + i] * h0r[i];
                    hn += Whh0[(40 + kk) * HN + i] * h0r[i];
                }
                float rr = sigf(ar + hr);
                float zz = sigf(az + hz);
                float nn = tanh_fast(an + rr * hn);
                float hprev = h0s[p][kk][l];
                float hnew = (1.0f - zz) * nn + zz * hprev;
                h0s[q][kk][l] = hnew;
                if (u == NS - 1) hf0[(size_t)b * HN + kk] = hnew;
            }
        }

        if (u >= 1) {
            // ---- layer 1: h1(u-1) for k0,k1; input = h0(u-1) = h0r ----
            float h1r[HN];
            #pragma unroll
            for (int i = 0; i < HN; ++i) h1r[i] = h1s[p][i][l];
            #pragma unroll
            for (int c = 0; c < 2; ++c) {
                const int kk = (c == 0) ? k0 : k1;
                float ar = bih1[kk], az = bih1[20 + kk], an = bih1[40 + kk];
                float hr = bhh1[kk], hz = bhh1[20 + kk], hn = bhh1[40 + kk];
                #pragma unroll
                for (int i = 0; i < HN; ++i) {
                    ar += Wih1[kk * HN + i] * h0r[i];
                    az += Wih1[(20 + kk) * HN + i] * h0r[i];
                    an += Wih1[(40 + kk) * HN + i] * h0r[i];
                    hr += Whh1[kk * HN + i] * h1r[i];
                    hz += Whh1[(20 + kk) * HN + i] * h1r[i];
                    hn += Whh1[(40 + kk) * HN + i] * h1r[i];
                }
                float rr = sigf(ar + hr);
                float zz = sigf(az + hz);
                float nn = tanh_fast(an + rr * hn);
                float hprev = h1s[p][kk][l];
                float hnew = (1.0f - zz) * nn + zz * hprev;
                h1s[q][kk][l] = hnew;
                enc[((size_t)(u - 1) * HN + kk) * NB + b] = hnew;
                if (u == NS) hf1[(size_t)b * HN + kk] = hnew;
            }
        }
        __syncthreads();
        p = q;
    }
}

__global__ __launch_bounds__(512)
void dec_kernel(const float* __restrict__ dWih0, const float* __restrict__ dWhh0,
                const float* __restrict__ dbih0, const float* __restrict__ dbhh0,
                const float* __restrict__ dWih1, const float* __restrict__ dWhh1,
                const float* __restrict__ dbih1, const float* __restrict__ dbhh1,
                const float* __restrict__ emb,  const float* __restrict__ qW,
                const float* __restrict__ qb,   const float* __restrict__ combW,
                const float* __restrict__ combb, const float* __restrict__ outW,
                const float* __restrict__ outb,
                const float* __restrict__ enc, const float* __restrict__ hf0,
                const float* __restrict__ hf1, float* __restrict__ out)
{
    __shared__ float hd0[HN][32], hd1[HN][32];   // transposed state
    __shared__ float gs[4 * HN][32];             // gate pre-acts
    __shared__ float bufA[32][129];              // attn weights / logits (row=batch)
    __shared__ float bufE[HN][32];               // emb -> query
    __shared__ float bufC[HN][32];               // context
    __shared__ float bufM[HN][32];               // comb
    __shared__ float redM[32][17], redS[32][17];
    __shared__ float lmax[32][17];
    __shared__ int   lidx[32][17];
    __shared__ int   toks[32];

    const int tid = threadIdx.x;
    const int sl  = tid >> 5;     // slot 0..15 (half-wave)
    const int ln  = tid & 31;     // batch within block
    const int b0  = blockIdx.x * 32;
    const int b   = b0 + ln;

    for (int idx = tid; idx < 32 * HN; idx += 512) {
        int e = idx / HN, k = idx % HN;
        hd0[k][e] = hf0[(size_t)(b0 + e) * HN + k];
        hd1[k][e] = hf1[(size_t)(b0 + e) * HN + k];
    }
    if (tid < 32) toks[tid] = 0;
    __syncthreads();

    for (int s = 0; s < NDEC; ++s) {
        // ---- embedding ----
        for (int k = sl; k < HN; k += 16) bufE[k][ln] = emb[toks[ln] * HN + k];
        __syncthreads();

        // ---- GRU layer 0 ----
        {
            float er[HN], hr[HN];
            #pragma unroll
            for (int i = 0; i < HN; ++i) { er[i] = bufE[i][ln]; hr[i] = hd0[i][ln]; }
            for (int j = sl; j < 60; j += 16) {
                const float4* wi = (const float4*)(dWih0 + j * HN);
                const float4* wh = (const float4*)(dWhh0 + j * HN);
                float ax = dbih0[j], ah = dbhh0[j];
                #pragma unroll
                for (int qq = 0; qq < 5; ++qq) {
                    float4 a4 = wi[qq], h4 = wh[qq];
                    ax += a4.x*er[4*qq] + a4.y*er[4*qq+1] + a4.z*er[4*qq+2] + a4.w*er[4*qq+3];
                    ah += h4.x*hr[4*qq] + h4.y*hr[4*qq+1] + h4.z*hr[4*qq+2] + h4.w*hr[4*qq+3];
                }
                if (j < 40) gs[j][ln] = ax + ah;
                else { gs[j][ln] = ax; gs[j + 20][ln] = ah; }
            }
        }
        __syncthreads();
        for (int k = sl; k < HN; k += 16) {
            float r = sigf(gs[k][ln]);
            float z = sigf(gs[20 + k][ln]);
            float n = tanh_fast(gs[40 + k][ln] + r * gs[60 + k][ln]);
            hd0[k][ln] = (1.0f - z) * n + z * hd0[k][ln];
        }
        __syncthreads();

        // ---- GRU layer 1 ----
        {
            float er[HN], hr[HN];
            #pragma unroll
            for (int i = 0; i < HN; ++i) { er[i] = hd0[i][ln]; hr[i] = hd1[i][ln]; }
            for (int j = sl; j < 60; j += 16) {
                const float4* wi = (const float4*)(dWih1 + j * HN);
                const float4* wh = (const float4*)(dWhh1 + j * HN);
                float ax = dbih1[j], ah = dbhh1[j];
                #pragma unroll
                for (int qq = 0; qq < 5; ++qq) {
                    float4 a4 = wi[qq], h4 = wh[qq];
                    ax += a4.x*er[4*qq] + a4.y*er[4*qq+1] + a4.z*er[4*qq+2] + a4.w*er[4*qq+3];
                    ah += h4.x*hr[4*qq] + h4.y*hr[4*qq+1] + h4.z*hr[4*qq+2] + h4.w*hr[4*qq+3];
                }
                if (j < 40) gs[j][ln] = ax + ah;
                else { gs[j][ln] = ax; gs[j + 20][ln] = ah; }
            }
        }
        __syncthreads();
        for (int k = sl; k < HN; k += 16) {
            float r = sigf(gs[k][ln]);
            float z = sigf(gs[20 + k][ln]);
            float n = tanh_fast(gs[40 + k][ln] + r * gs[60 + k][ln]);
            hd1[k][ln] = (1.0f - z) * n + z * hd1[k][ln];
        }
        __syncthreads();

        float h1r[HN];
        #pragma unroll
        for (int i = 0; i < HN; ++i) h1r[i] = hd1[i][ln];

        // ---- query -> bufE ----
        for (int k = sl; k < HN; k += 16) {
            const float4* wq = (const float4*)(qW + k * HN);
            float a = qb[k];
            #pragma unroll
            for (int qq = 0; qq < 5; ++qq) {
                float4 q4 = wq[qq];
                a += q4.x*h1r[4*qq] + q4.y*h1r[4*qq+1] + q4.z*h1r[4*qq+2] + q4.w*h1r[4*qq+3];
            }
            bufE[k][ln] = a;
        }
        __syncthreads();

        // ---- scores + softmax: slot owns t in [8*sl, 8*sl+8) ----
        {
            float qr[HN];
            #pragma unroll
            for (int i = 0; i < HN; ++i) qr[i] = bufE[i][ln];
            const int t0 = sl * 8;
            float sreg[8];
            float mx = -1e30f;
            #pragma unroll
            for (int u = 0; u < 8; ++u) {
                int t = t0 + u;
                float a = 0.0f;
                #pragma unroll
                for (int k = 0; k < HN; ++k)
                    a += qr[k] * enc[((size_t)t * HN + k) * NB + b];
                sreg[u] = a;
                mx = fmaxf(mx, a);
            }
            redM[ln][sl] = mx;
            __syncthreads();
            float M = redM[ln][0];
            #pragma unroll
            for (int j = 1; j < 16; ++j) M = fmaxf(M, redM[ln][j]);
            float ssum = 0.0f;
            #pragma unroll
            for (int u = 0; u < 8; ++u) {
                float e = __expf(sreg[u] - M);
                sreg[u] = e;
                ssum += e;
            }
            redS[ln][sl] = ssum;
            __syncthreads();
            float S = 0.0f;
            #pragma unroll
            for (int j = 0; j < 16; ++j) S += redS[ln][j];
            float inv = 1.0f / S;
            #pragma unroll
            for (int u = 0; u < 8; ++u) bufA[ln][t0 + u] = sreg[u] * inv;
        }
        __syncthreads();

        // ---- attention-weight output (coalesced over t) ----
        for (int it = 0; it < 8; ++it) {
            int idx = it * 512 + tid;
            int e = idx >> 7, tt = idx & 127;
            out[ATTN_OFF + (size_t)s * NB * NS + (size_t)(b0 + e) * NS + tt] = bufA[e][tt];
        }

        // ---- context ----
        for (int k = sl; k < HN; k += 16) {
            float acc = 0.0f;
            for (int t = 0; t < NS; ++t)
                acc += bufA[ln][t] * enc[((size_t)t * HN + k) * NB + b];
            bufC[k][ln] = acc;
        }
        __syncthreads();

        // ---- comb ----
        {
            float cr[HN];
            #pragma unroll
            for (int i = 0; i < HN; ++i) cr[i] = bufC[i][ln];
            for (int k = sl; k < HN; k += 16) {
                const float4* wc = (const float4*)(combW + k * 2 * HN);
                float a = combb[k];
                #pragma unroll
                for (int qq = 0; qq < 5; ++qq) {
                    float4 c4 = wc[qq];
                    a += c4.x*h1r[4*qq] + c4.y*h1r[4*qq+1] + c4.z*h1r[4*qq+2] + c4.w*h1r[4*qq+3];
                }
                #pragma unroll
                for (int qq = 0; qq < 5; ++qq) {
                    float4 c4 = wc[5 + qq];
                    a += c4.x*cr[4*qq] + c4.y*cr[4*qq+1] + c4.z*cr[4*qq+2] + c4.w*cr[4*qq+3];
                }
                bufM[k][ln] = a;
            }
        }
        __syncthreads();

        // ---- logits + per-slot argmax: slot owns v in [8*sl, 8*sl+8) ----
        {
            float cr[HN];
            #pragma unroll
            for (int i = 0; i < HN; ++i) cr[i] = bufM[i][ln];
            float best = -1e30f; int bi = 0;
            #pragma unroll
            for (int u = 0; u < 8; ++u) {
                int v = sl * 8 + u;
                const float4* wo = (const float4*)(outW + v * HN);
                float a = outb[v];
                #pragma unroll
                for (int qq = 0; qq < 5; ++qq) {
                    float4 o4 = wo[qq];
                    a += o4.x*cr[4*qq] + o4.y*cr[4*qq+1] + o4.z*cr[4*qq+2] + o4.w*cr[4*qq+3];
                }
                bufA[ln][v] = a;
                if (a > best) { best = a; bi = v; }   // strict >, ascending v: first max
            }
            lmax[ln][sl] = best;
            lidx[ln][sl] = bi;
        }
        __syncthreads();

        // ---- logits write (coalesced) + argmax combine ----
        for (int it = 0; it < 8; ++it) {
            int idx = it * 512 + tid;
            int e = idx >> 7, v = idx & 127;
            out[(size_t)(b0 + e) * (NDEC * NVOCAB) + s * NVOCAB + v] = bufA[e][v];
        }
        if (tid < 32) {
            float bb = lmax[tid][0]; int ii = lidx[tid][0];
            #pragma unroll
            for (int j = 1; j < 16; ++j)
                if (lmax[tid][j] > bb) { bb = lmax[tid][j]; ii = lidx[tid][j]; }
            toks[tid] = ii;
        }
        __syncthreads();
    }

    // ---- final hidden state [2][B][H] ----
    for (int idx = tid; idx < 32 * HN; idx += 512) {
        int e = idx / HN, k = idx % HN;
        out[HID_OFF + (size_t)(b0 + e) * HN + k] = hd0[k][e];
        out[HID_OFF + (size_t)NB * HN + (size_t)(b0 + e) * HN + k] = hd1[k][e];
    }
}

extern "C" void kernel_launch(void* const* d_in, const int* in_sizes, int n_in,
                              void* d_out, int out_size, void* d_ws, size_t ws_size,
                              hipStream_t stream)
{
    const float* x     = (const float*)d_in[0];
    const float* eWih0 = (const float*)d_in[1];
    const float* eWhh0 = (const float*)d_in[2];
    const float* ebih0 = (const float*)d_in[3];
    const float* ebhh0 = (const float*)d_in[4];
    const float* eWih1 = (const float*)d_in[5];
    const float* eWhh1 = (const float*)d_in[6];
    const float* ebih1 = (const float*)d_in[7];
    const float* ebhh1 = (const float*)d_in[8];
    const float* dWih0 = (const float*)d_in[9];
    const float* dWhh0 = (const float*)d_in[10];
    const float* dbih0 = (const float*)d_in[11];
    const float* dbhh0 = (const float*)d_in[12];
    const float* dWih1 = (const float*)d_in[13];
    const float* dWhh1 = (const float*)d_in[14];
    const float* dbih1 = (const float*)d_in[15];
    const float* dbhh1 = (const float*)d_in[16];
    const float* emb   = (const float*)d_in[17];
    const float* qW    = (const float*)d_in[18];
    const float* qb    = (const float*)d_in[19];
    const float* combW = (const float*)d_in[20];
    const float* combb = (const float*)d_in[21];
    const float* outW  = (const float*)d_in[22];
    const float* outb  = (const float*)d_in[23];

    const size_t need = ((size_t)NS * HN * NB + 2 * (size_t)NB * HN) * sizeof(float);
    if (ws_size < need) return;

    float* ws  = (float*)d_ws;
    float* enc = ws;
    float* hf0 = ws + (size_t)NS * HN * NB;
    float* hf1 = hf0 + (size_t)NB * HN;

    enc_kernel<<<128, 640, 0, stream>>>(x, eWih0, eWhh0, ebih0, ebhh0,
                                        eWih1, eWhh1, ebih1, ebhh1,
                                        enc, hf0, hf1);
    dec_kernel<<<256, 512, 0, stream>>>(dWih0, dWhh0, dbih0, dbhh0,
                                        dWih1, dWhh1, dbih1, dbhh1,
                                        emb, qW, qb, combW, combb, outW, outb,
                                        enc, hf0, hf1, (float*)d_out);
}